// Round 5
// baseline (217.495 us; speedup 1.0000x reference)
//
#include <hip/hip_runtime.h>
#include <math.h>

#define NN 4
#define CCH 128
#define HH 96
#define WW 96
#define SS (HH*WW)          // 9216
#define GG 4
#define GC 32
#define PP 9
#define NPIX (NN*HH*WW)     // 36864

typedef short bf16x8 __attribute__((ext_vector_type(8)));
typedef float f32x4 __attribute__((ext_vector_type(4)));
typedef unsigned short u16;
typedef unsigned int u32;

static __device__ __forceinline__ u16 f2bf(float f) {
  unsigned u = __builtin_bit_cast(unsigned, f);
  unsigned r = (u + 0x7fffu + ((u >> 16) & 1u)) >> 16;  // RNE
  return (u16)r;
}
static __device__ __forceinline__ float bf2f(u16 v) {
  return __builtin_bit_cast(float, ((u32)v) << 16);
}

// ---------------- prep: transpose + bf16-convert weights
// rows 0..127: w_inT; 128..239: w_omT (c<72 off, 72..107 mask, pad 0); 240..367: w_outT
__global__ __launch_bounds__(128) void k_prep(const float* __restrict__ w_in,
    const float* __restrict__ w_off, const float* __restrict__ w_mask,
    const float* __restrict__ w_out,
    u16* __restrict__ w_inT, u16* __restrict__ w_omT, u16* __restrict__ w_outT) {
  int r = blockIdx.x, k = threadIdx.x;
  if (r < 128) {
    w_inT[r*128 + k] = f2bf(w_in[k*128 + r]);
  } else if (r < 240) {
    int c = r - 128;
    float v = 0.f;
    if (c < 72) v = w_off[k*72 + c];
    else if (c < 108) v = w_mask[k*36 + (c - 72)];
    w_omT[c*128 + k] = f2bf(v);
  } else {
    int c = r - 240;
    w_outT[c*128 + k] = f2bf(w_out[k*128 + c]);
  }
}

// ---------------- Transpose in: x NCHW -> xTb (bf16 NHWC)
__global__ __launch_bounds__(256) void k_tr_in(const float* __restrict__ x,
                                               u16* __restrict__ xTb) {
  __shared__ float tile[32][33];
  int n = blockIdx.z;
  int cs = blockIdx.y * 32;
  int ps = blockIdx.x * 32;
  int tx = threadIdx.x;
  int ty = threadIdx.y;
  const float* src = x + ((size_t)n*CCH)*SS;
  #pragma unroll
  for (int i = 0; i < 4; ++i) {
    int r = ty + i*8;
    tile[r][tx] = src[(size_t)(cs + r)*SS + ps + tx];
  }
  __syncthreads();
  u16* dstb = xTb + (size_t)n*SS*CCH;
  #pragma unroll
  for (int i = 0; i < 4; ++i) {
    int r = ty + i*8;
    dstb[(size_t)(ps + r)*CCH + cs + tx] = f2bf(tile[tx][r]);
  }
}

// ---------------- input projection: xpb = xTb @ w_inT^T + b_in  (MFMA, 64px/block)
__global__ __launch_bounds__(256) void k_proj_mfma(const u16* __restrict__ xTb,
    const u16* __restrict__ wT, const float* __restrict__ bias,
    u16* __restrict__ xpb) {
  int t = threadIdx.x;
  int wv = t >> 6, l = t & 63;
  int c16 = l & 15, kq = l >> 4;
  int px0 = blockIdx.x*64 + wv*16;
  const u16* arow = xTb + (size_t)(px0 + c16)*CCH + kq*8;
  f32x4 acc[8] = {};
  #pragma unroll
  for (int ks = 0; ks < 4; ++ks) {
    bf16x8 a = *(const bf16x8*)(arow + ks*32);
    #pragma unroll
    for (int nt = 0; nt < 8; ++nt) {
      bf16x8 b = *(const bf16x8*)(wT + (size_t)(nt*16 + c16)*CCH + ks*32 + kq*8);
      acc[nt] = __builtin_amdgcn_mfma_f32_16x16x32_bf16(a, b, acc[nt], 0, 0, 0);
    }
  }
  #pragma unroll
  for (int nt = 0; nt < 8; ++nt) {
    int c = nt*16 + c16;
    float bs = bias[c];
    #pragma unroll
    for (int r = 0; r < 4; ++r) {
      int px = px0 + kq*4 + r;
      xpb[(size_t)px*CCH + c] = f2bf(acc[nt][r] + bs);
    }
  }
}

// ---------------- dwconv3x3 + LN + GELU -> x1b bf16 (8 px/block), bf16 input
__global__ __launch_bounds__(128) void k_dwln8(const u16* __restrict__ xTb,
    const float* __restrict__ dw_w, const float* __restrict__ dw_b,
    const float* __restrict__ ln_g, const float* __restrict__ ln_b,
    u16* __restrict__ x1b) {
  __shared__ float rs[8][2][2];
  int blk = blockIdx.x;
  const int W8 = WW/8;
  int w0 = (blk % W8) * 8;
  int h  = (blk / W8) % HH;
  int n  = blk / (W8*HH);
  int c  = threadIdx.x;
  const u16* src = xTb + (size_t)n*SS*CCH + c;
  float r[3][10];
  #pragma unroll
  for (int kh = 0; kh < 3; ++kh) {
    int yy = h - 1 + kh;
    bool yok = (yy >= 0 && yy < HH);
    #pragma unroll
    for (int i = 0; i < 10; ++i) {
      int xx = w0 - 1 + i;
      r[kh][i] = (yok && xx >= 0 && xx < WW) ? bf2f(src[(size_t)(yy*WW + xx)*CCH]) : 0.f;
    }
  }
  float wt[9];
  #pragma unroll
  for (int j = 0; j < 9; ++j) wt[j] = dw_w[c*9 + j];
  float bias = dw_b[c], lg = ln_g[c], lb = ln_b[c];
  float sv[8];
  #pragma unroll
  for (int j = 0; j < 8; ++j) {
    float s = bias;
    #pragma unroll
    for (int kh = 0; kh < 3; ++kh)
      #pragma unroll
      for (int kw = 0; kw < 3; ++kw)
        s = fmaf(r[kh][j + kw], wt[kh*3 + kw], s);
    sv[j] = s;
    float s1 = s, s2 = s*s;
    #pragma unroll
    for (int m = 32; m >= 1; m >>= 1) {
      s1 += __shfl_xor(s1, m);
      s2 += __shfl_xor(s2, m);
    }
    if ((c & 63) == 0) { rs[j][c>>6][0] = s1; rs[j][c>>6][1] = s2; }
  }
  __syncthreads();
  size_t pix0 = (size_t)(n*HH + h)*WW + w0;
  #pragma unroll
  for (int j = 0; j < 8; ++j) {
    float sum = rs[j][0][0] + rs[j][1][0];
    float sq  = rs[j][0][1] + rs[j][1][1];
    float mean = sum * (1.f/128.f);
    float var  = sq * (1.f/128.f) - mean*mean;
    float v = (sv[j] - mean) * rsqrtf(var + 1e-5f) * lg + lb;
    float g = 0.5f * v * (1.f + erff(v * 0.70710678f));
    x1b[(pix0 + j)*CCH + c] = f2bf(g);
  }
}

// ---------------- fused: om heads (MFMA) + softmax + DCN sampling + out proj (MFMA)
//                  + BN + SiLU + NCHW store.  32 px/block, 256 threads.
__global__ __launch_bounds__(256) void k_fuse(const u16* __restrict__ x1b,
    const u16* __restrict__ xpb,
    const u16* __restrict__ wTom, const u16* __restrict__ wTout,
    const float* __restrict__ b_off, const float* __restrict__ b_mask,
    const float* __restrict__ b_out,
    const float* __restrict__ bn_g, const float* __restrict__ bn_b,
    const float* __restrict__ bn_mean, const float* __restrict__ bn_var,
    float* __restrict__ y) {
  __shared__ float bufA[32][132];   // phase A: off/mask logits; phase C: final f32
  __shared__ u16  dtile[32][136];   // phase B output: dcn results bf16
  int t = threadIdx.x;
  int wv = t >> 6, l = t & 63;
  int c16 = l & 15, kq = l >> 4;
  int s0 = blockIdx.x * 32;
  int n = s0 / SS, rem = s0 % SS;

  // ---- Phase A: offset/mask heads via MFMA (7 col-tiles over 4 waves)
  {
    int pxh = wv & 1;
    int ntb = (wv >> 1) * 4;
    int ntn = (wv >> 1) ? 3 : 4;
    int px0 = s0 + pxh*16;
    const u16* arow = x1b + (size_t)(px0 + c16)*CCH + kq*8;
    f32x4 acc[4] = {};
    #pragma unroll
    for (int ks = 0; ks < 4; ++ks) {
      bf16x8 a = *(const bf16x8*)(arow + ks*32);
      for (int j = 0; j < 4; ++j) {
        if (j >= ntn) break;
        int nt = ntb + j;
        bf16x8 b = *(const bf16x8*)(wTom + (size_t)(nt*16 + c16)*CCH + ks*32 + kq*8);
        acc[j] = __builtin_amdgcn_mfma_f32_16x16x32_bf16(a, b, acc[j], 0, 0, 0);
      }
    }
    for (int j = 0; j < 4; ++j) {
      if (j >= ntn) break;
      int c = ntb*16 + j*16 + c16;
      float bs = (c < 72) ? b_off[c] : ((c < 108) ? b_mask[c - 72] : 0.f);
      #pragma unroll
      for (int r = 0; r < 4; ++r)
        bufA[pxh*16 + kq*4 + r][c] = acc[j][r] + bs;
    }
  }
  __syncthreads();

  // ---- Phase A2: per-(px,group) softmax over 9 logits (in place)
  if (t < 128) {
    int px = t >> 2, g = t & 3;
    float mx = -1e30f;
    #pragma unroll
    for (int q = 0; q < PP; ++q) mx = fmaxf(mx, bufA[px][72 + g*PP + q]);
    float e[PP]; float sum = 0.f;
    #pragma unroll
    for (int q = 0; q < PP; ++q) { e[q] = __expf(bufA[px][72 + g*PP + q] - mx); sum += e[q]; }
    float inv = 1.f / sum;
    #pragma unroll
    for (int q = 0; q < PP; ++q) bufA[px][72 + g*PP + q] = e[q] * inv;
  }
  __syncthreads();

  // ---- Phase B: bilinear sampling from bf16 xpb (L2-resident). 512 tasks.
  #pragma unroll
  for (int rep = 0; rep < 2; ++rep) {
    int id = t + rep*256;
    int pxl = id >> 4;            // 0..31
    int unit = id & 15;           // 16 units of 8 channels
    int g = unit >> 2;
    int ch0 = g*GC + (unit & 3)*8;
    int pix = s0 + pxl;
    int w = pix % WW; int h = (pix / WW) % HH;
    const u16* basep = xpb + (size_t)n*SS*CCH + ch0;
    float a8[8] = {};
    #pragma unroll
    for (int p = 0; p < PP; ++p) {
      float offx = bufA[pxl][(g*PP + p)*2 + 0];
      float offy = bufA[pxl][(g*PP + p)*2 + 1];
      float mval = bufA[pxl][72 + g*PP + p];
      float ix = (float)w + 1.0f + (float)(p / 3 - 1) + offx;
      float iy = (float)h + 1.0f + (float)(p % 3 - 1) + offy;
      float x0f = floorf(ix), y0f = floorf(iy);
      float wx1 = ix - x0f, wx0 = 1.f - wx1;
      float wy1 = iy - y0f, wy0 = 1.f - wy1;
      int x0i = (int)x0f, y0i = (int)y0f;
      int ox0 = x0i - 1, oy0 = y0i - 1;   // padded -> original
      int ox1 = x0i,     oy1 = y0i;
      float v8[8] = {};
      bool y0ok = (oy0 >= 0 && oy0 < HH), y1ok = (oy1 >= 0 && oy1 < HH);
      bool x0ok = (ox0 >= 0 && ox0 < WW), x1ok = (ox1 >= 0 && ox1 < WW);
      #pragma unroll
      for (int corner = 0; corner < 4; ++corner) {
        int oy = (corner < 2) ? oy0 : oy1;
        int ox = (corner & 1) ? ox1 : ox0;
        bool ok = ((corner < 2) ? y0ok : y1ok) && ((corner & 1) ? x1ok : x0ok);
        float wgt = ((corner < 2) ? ((corner & 1) ? wy0*wx1 : wy0*wx0)
                                  : ((corner & 1) ? wy1*wx1 : wy1*wx0));
        if (ok) {
          bf16x8 raw = *(const bf16x8*)(basep + (size_t)(oy*WW + ox)*CCH);
          u32 uw[4];
          *(bf16x8*)uw = raw;
          #pragma unroll
          for (int j = 0; j < 4; ++j) {
            float lo = __builtin_bit_cast(float, uw[j] << 16);
            float hi = __builtin_bit_cast(float, uw[j] & 0xffff0000u);
            v8[2*j]   = fmaf(wgt, lo, v8[2*j]);
            v8[2*j+1] = fmaf(wgt, hi, v8[2*j+1]);
          }
        }
      }
      #pragma unroll
      for (int j = 0; j < 8; ++j) a8[j] = fmaf(mval, v8[j], a8[j]);
    }
    #pragma unroll
    for (int j = 0; j < 4; ++j) {
      u32 packed = (u32)f2bf(a8[2*j]) | ((u32)f2bf(a8[2*j+1]) << 16);
      *(u32*)&dtile[pxl][ch0 + 2*j] = packed;
    }
  }
  __syncthreads();

  // ---- Phase C: output projection MFMA from LDS dtile + BN + SiLU
  {
    int pxh = wv & 1;
    int ntb = (wv >> 1) * 4;
    int px0loc = pxh*16;
    f32x4 acc[4] = {};
    #pragma unroll
    for (int ks = 0; ks < 4; ++ks) {
      bf16x8 a = *(const bf16x8*)&dtile[px0loc + c16][kq*8 + ks*32];
      #pragma unroll
      for (int j = 0; j < 4; ++j) {
        int nt = ntb + j;
        bf16x8 b = *(const bf16x8*)(wTout + (size_t)(nt*16 + c16)*CCH + ks*32 + kq*8);
        acc[j] = __builtin_amdgcn_mfma_f32_16x16x32_bf16(a, b, acc[j], 0, 0, 0);
      }
    }
    __syncthreads();   // dtile reads done; bufA reuse safe
    #pragma unroll
    for (int j = 0; j < 4; ++j) {
      int c = ntb*16 + j*16 + c16;
      float sc = rsqrtf(bn_var[c] + 1e-5f) * bn_g[c];
      float sh = bn_b[c] - bn_mean[c] * sc;
      float bs = b_out[c];
      #pragma unroll
      for (int r = 0; r < 4; ++r) {
        float v = (acc[j][r] + bs) * sc + sh;
        float sig = 1.f / (1.f + __expf(-v));
        bufA[px0loc + kq*4 + r][c] = v * sig;
      }
    }
  }
  __syncthreads();

  // ---- store: NCHW coalesced (32 contiguous pixels per channel)
  {
    int pxl = t & 31, cb = t >> 5;
    float* dst = y + ((size_t)n*CCH)*SS + rem;
    #pragma unroll
    for (int i = 0; i < 16; ++i) {
      int c = cb*16 + i;
      dst[(size_t)c*SS + pxl] = bufA[pxl][c];
    }
  }
}

extern "C" void kernel_launch(void* const* d_in, const int* in_sizes, int n_in,
                              void* d_out, int out_size, void* d_ws, size_t ws_size,
                              hipStream_t stream) {
  const float* x       = (const float*)d_in[0];
  const float* dw_w    = (const float*)d_in[1];
  const float* dw_b    = (const float*)d_in[2];
  const float* ln_g    = (const float*)d_in[3];
  const float* ln_b    = (const float*)d_in[4];
  const float* w_off   = (const float*)d_in[5];
  const float* b_off   = (const float*)d_in[6];
  const float* w_mask  = (const float*)d_in[7];
  const float* b_mask  = (const float*)d_in[8];
  const float* w_in    = (const float*)d_in[9];
  const float* b_in    = (const float*)d_in[10];
  const float* w_out   = (const float*)d_in[11];
  const float* b_out   = (const float*)d_in[12];
  const float* bn_g    = (const float*)d_in[13];
  const float* bn_b    = (const float*)d_in[14];
  const float* bn_mean = (const float*)d_in[15];
  const float* bn_var  = (const float*)d_in[16];
  float* y = (float*)d_out;

  u16* xTb = (u16*)d_ws;                       // NPIX*128 bf16
  u16* xpb = xTb + (size_t)NPIX*CCH;           // NPIX*128 bf16
  u16* x1b = xpb + (size_t)NPIX*CCH;           // NPIX*128 bf16
  u16* wbuf = x1b + (size_t)NPIX*CCH;          // (128+112+128)*128 bf16
  u16* w_inT  = wbuf;
  u16* w_omT  = w_inT + 128*128;
  u16* w_outT = w_omT + 112*128;

  dim3 trg(SS/32, CCH/32, NN), trb(32, 8);
  k_prep<<<368, 128, 0, stream>>>(w_in, w_off, w_mask, w_out, w_inT, w_omT, w_outT);
  k_tr_in<<<trg, trb, 0, stream>>>(x, xTb);
  k_proj_mfma<<<NPIX/64, 256, 0, stream>>>(xTb, w_inT, b_in, xpb);
  k_dwln8<<<NPIX/8, 128, 0, stream>>>(xTb, dw_w, dw_b, ln_g, ln_b, x1b);
  k_fuse<<<NPIX/32, 256, 0, stream>>>(x1b, xpb, w_omT, w_outT,
                                      b_off, b_mask, b_out,
                                      bn_g, bn_b, bn_mean, bn_var, y);
}